// Round 21
// baseline (313.369 us; speedup 1.0000x reference)
//
#include <hip/hip_runtime.h>
#include <math.h>

// ---------------- problem constants ----------------
#define NN 512
#define EE 2048
#define IN_F 64
#define HID 256
#define MSGD 128
#define OUTC 16
#define MAX_STEPS 5120

// ---------------- kernel config ----------------
#define NWGA 256      // phase-A WGs (node & 255 ownership)
#define MAXD 64       // padded neighbor-row stride
#define NCLUS 32      // phase-B clusters
#define WPC 8         // phase-B WGs per cluster (32 units x 4 gates = 128 rows each)
#define KSLOT 16      // chain slots per cluster

typedef _Float16 h2v __attribute__((ext_vector_type(2)));
typedef _Float16 f16x8 __attribute__((ext_vector_type(8)));
typedef float f32x4 __attribute__((ext_vector_type(4)));

static __device__ __forceinline__ float fdot2u(unsigned int w, unsigned int a, float c) {
    return __builtin_amdgcn_fdot2(__builtin_bit_cast(h2v, w),
                                  __builtin_bit_cast(h2v, a), c, false);
}
static __device__ __forceinline__ unsigned int pkh(float a, float b) {
    h2v h; h.x = (_Float16)a; h.y = (_Float16)b;     // RTN converts
    return __builtin_bit_cast(unsigned int, h);
}

// ---------------- device globals (all rewritten every call) ----------------
__device__ int   g_nbrs64[NN][MAXD];
__device__ int   g_degs[NN];
__device__ int4  g_sched[MAX_STEPS];     // x=node, y=t(enqueue base), z=deg
__device__ int   g_mready[MAX_STEPS];
__device__ int   g_S0, g_T, g_P;
__device__ int   g_alist[NWGA][MAX_STEPS];
__device__ int   g_acnt[NWGA];
__device__ int   g_noff[NN + 1];
__device__ int   g_nlist[MAX_STEPS];     // phase-B steps grouped by node
__device__ int   g_border[NN];           // phase-B nodes sorted by chain length desc
__device__ int   g_nB;
__device__ int   g_tflag[NCLUS][WPC];    // per-cluster per-WG tick flags (init -1)
__device__ float g_qmsgs[MAX_STEPS][MSGD];
__device__ uint4 g_qmsgP4[MAX_STEPS][16];   // f16-packed messages (phase-B consumed)
__device__ uint4 g_hpk4[2][NN][32];         // f16-packed h, tick-parity double buffer
__device__ float g_hid[NN][HID];
__device__ float g_cell[NN][HID];
__device__ uint4 g_WTph[112 * 512];      // f16-packed gates [colquad q][rowpair r] (phase A)
__device__ uint4 g_WBm[WPC * 8 * 12 * 64]; // phase-B MFMA A-frags [j][wave][kt][lane]
__device__ unsigned int g_nmTph[192 * 128]; // f16-packed nm: [colpair cp][out o]
__device__ float g_bias[1024];           // b_ih + b_hh

__device__ __forceinline__ float sigm(float x) { return 1.0f / (1.0f + expf(-x)); }
__device__ __forceinline__ float gw(const float* W_ih, const float* W_hh, int row, int c) {
    return (c < MSGD) ? W_ih[row * MSGD + c] : W_hh[row * HID + (c - MSGD)];
}

// ---------------- fused setup: encoder | phase-A weight pack | phase-B frags | nbr ----------------
__global__ __launch_bounds__(256) void k_setup(const float* __restrict__ xa,
                                               const float* __restrict__ enc_W,
                                               const float* __restrict__ enc_b,
                                               const float* __restrict__ W_ih,
                                               const float* __restrict__ W_hh,
                                               const float* __restrict__ b_ih,
                                               const float* __restrict__ b_hh,
                                               const float* __restrict__ nm_W,
                                               const int* __restrict__ edge_index) {
    const int b = blockIdx.x, tid = threadIdx.x;
    if (b < 512) {                 // encoder: hid = xa @ enc_W^T + enc_b; cell = 0
        const int gid = b * 256 + tid;
        const int n = gid >> 8, ccol = gid & 255;
        const float* x = xa + n * IN_F;
        const float* w = enc_W + ccol * IN_F;
        float acc = enc_b[ccol];
#pragma unroll 8
        for (int j = 0; j < IN_F; ++j) acc += x[j] * w[j];
        g_hid[n][ccol] = acc;
        g_cell[n][ccol] = 0.0f;
    } else if (b < 1024) {         // phase-A weight pack (row-pair r)
        const int r = b - 512;
        for (int q = tid; q < 96; q += 256) {
            uint4 v;
            v.x = pkh(gw(W_ih, W_hh, 2 * r, 4 * q),     gw(W_ih, W_hh, 2 * r, 4 * q + 1));
            v.y = pkh(gw(W_ih, W_hh, 2 * r + 1, 4 * q), gw(W_ih, W_hh, 2 * r + 1, 4 * q + 1));
            v.z = pkh(gw(W_ih, W_hh, 2 * r, 4 * q + 2), gw(W_ih, W_hh, 2 * r, 4 * q + 3));
            v.w = pkh(gw(W_ih, W_hh, 2 * r + 1, 4 * q + 2), gw(W_ih, W_hh, 2 * r + 1, 4 * q + 3));
            g_WTph[q * 512 + r] = v;
        }
        if (r < 192 && tid < 128)
            g_nmTph[r * 128 + tid] = pkh(nm_W[tid * 384 + 2 * r], nm_W[tid * 384 + 2 * r + 1]);
        if (r == 0)
            for (int g = tid; g < 1024; g += 256) g_bias[g] = b_ih[g] + b_hh[g];
    } else if (b < 1216) {         // phase-B MFMA A-fragments (4 frag-blocks per block)
        const int b4 = (b - 1024) * 4 + (tid >> 6);   // 0..767 = (j, wave, kt)
        const int lane = tid & 63;
        const int j = b4 / 96, rem = b4 - j * 96;
        const int w = rem / 12, kt = rem - w * 12;
        const int rl = 16 * w + (lane & 15);
        const int R = (rl >> 5) * 256 + (j << 5) + (rl & 31);
        const int kb = kt * 32 + (lane >> 4) * 8;
        unsigned int d[4];
#pragma unroll
        for (int q = 0; q < 4; ++q)
            d[q] = pkh(gw(W_ih, W_hh, R, kb + 2 * q), gw(W_ih, W_hh, R, kb + 2 * q + 1));
        uint4 v; v.x = d[0]; v.y = d[1]; v.z = d[2]; v.w = d[3];
        g_WBm[b4 * 64 + lane] = v;
    } else {                        // neighbor lists (node v)
        __shared__ unsigned int bits[16];
        const int v = b - 1216;
        if (tid < 16) bits[tid] = 0u;
        __syncthreads();
        for (int e = tid; e < EE; e += 256) {
            const int s = edge_index[e], d = edge_index[EE + e];
            if (s == v) atomicOr(&bits[d >> 5], 1u << (d & 31));
            if (d == v) atomicOr(&bits[s >> 5], 1u << (s & 31));
        }
        __syncthreads();
        if (tid == 0) {
            int cnt = 0;
            for (int w = 0; w < 16; ++w) {
                unsigned int bb = bits[w];
                while (bb) {
                    const int j = __ffs(bb) - 1;
                    bb &= bb - 1u;
                    if (cnt < MAXD) g_nbrs64[v][cnt++] = w * 32 + j;
                }
            }
            g_degs[v] = cnt;
        }
    }
}

// ---------------- schedule expansion: single block, parallel scans ----------------
__global__ __launch_bounds__(1024) void k_sched(const int* __restrict__ starts) {
    __shared__ int s_nx[MAX_STEPS];
    __shared__ int s_ny[MAX_STEPS];
    __shared__ int scanbuf[2][1024];
    __shared__ int s_deg[NN];
    __shared__ int s_off[NN + 1];
    __shared__ int s_csr[4160];
    __shared__ int s_nodes[NN];
    __shared__ int s_cnt[NN];
    __shared__ int s_misc[4];
    __shared__ int s_hist[64];
    const int tid = threadIdx.x;

    const int stt = (tid < NN && starts[tid] != 0) ? 1 : 0;
    const int dg0 = (tid < NN) ? g_degs[tid] : 0;
    if (tid < NN) s_deg[tid] = dg0;
    for (int i = tid; i < MAX_STEPS; i += 1024) s_ny[i] = 0x7fffffff;

    // ---- scan 1: degree prefix -> s_off (CSR offsets)
    scanbuf[0][tid] = dg0;
    __syncthreads();
    int src = 0;
    for (int off = 1; off < 1024; off <<= 1) {
        int v = scanbuf[src][tid];
        if (tid >= off) v += scanbuf[src][tid - off];
        scanbuf[src ^ 1][tid] = v;
        src ^= 1;
        __syncthreads();
    }
    if (tid <= NN) s_off[tid] = scanbuf[src][tid] - ((tid < NN) ? dg0 : 0);
    __syncthreads();

    // ---- scan 2: start-node compaction -> s_nodes, S0
    scanbuf[0][tid] = stt;
    __syncthreads();
    src = 0;
    for (int off = 1; off < 1024; off <<= 1) {
        int v = scanbuf[src][tid];
        if (tid >= off) v += scanbuf[src][tid - off];
        scanbuf[src ^ 1][tid] = v;
        src ^= 1;
        __syncthreads();
    }
    if (stt) s_nodes[scanbuf[src][tid] - 1] = tid;
    const int S0tot = scanbuf[src][1023];
    __syncthreads();

    // ---- stage CSR into LDS; init queue head
    if (tid < NN) {
        const int o = s_off[tid], dg = s_deg[tid];
        for (int e = 0; e < dg; ++e) s_csr[o + e] = g_nbrs64[tid][e];
    }
    const int S0 = (S0tot < MAX_STEPS) ? S0tot : MAX_STEPS;
    int known = S0;
    for (int i = tid; i < known; i += 1024) s_nx[i] = s_nodes[i];
    __syncthreads();

    // ---- round-expansion (message-independent), all in LDS
    for (int round = 0; round < 8 && known > 0; ++round) {
        const int C = (known + 1023) >> 10;
        const int base = tid * C;
        int lsum = 0;
        for (int j = 0; j < C; ++j) {
            int i = base + j;
            if (i < known) lsum += s_deg[s_nx[i]];
        }
        scanbuf[0][tid] = lsum;
        __syncthreads();
        src = 0;
        for (int off = 1; off < 1024; off <<= 1) {
            int v = scanbuf[src][tid];
            if (tid >= off) v += scanbuf[src][tid - off];
            scanbuf[src ^ 1][tid] = v;
            src ^= 1;
            __syncthreads();
        }
        const int excl = (tid == 0) ? 0 : scanbuf[src][tid - 1];
        const int total = scanbuf[src][1023];
        int t = S0 + excl;
        for (int j = 0; j < C; ++j) {
            int i = base + j;
            if (i < known) {
                const int nd = s_nx[i];
                const int dg = s_deg[nd], o = s_off[nd];
                s_ny[i] = t;
                for (int e = 0; e < dg; ++e) {
                    const int pos = t + e;
                    if (pos >= known && pos < MAX_STEPS) s_nx[pos] = s_csr[o + e];
                }
                t += dg;
            }
        }
        __syncthreads();
        int newknown = S0 + total;
        if (newknown > MAX_STEPS) newknown = MAX_STEPS;
        if (newknown == known) break;
        known = newknown;
    }
    __syncthreads();
    const int kn = known;
    if (tid == 0) s_misc[1] = kn;
    __syncthreads();
    for (int i = tid; i < kn; i += 1024)
        if (s_ny[i] <= i) atomicMin(&s_misc[1], i);        // first drained step
    __syncthreads();
    const int istar = s_misc[1];
    if (tid == 0) s_misc[2] = istar;
    __syncthreads();
    for (int i = tid; i < istar; i += 1024)
        if (s_ny[i] >= istar) atomicMin(&s_misc[2], i);    // first nothing-consumed producer
    __syncthreads();
    const int P = s_misc[2];

    // ---- write schedule (coalesced int4)
    for (int i = tid; i < MAX_STEPS; i += 1024) {
        int4 sc;
        if (i < kn) { sc.x = s_nx[i]; sc.y = s_ny[i]; sc.z = s_deg[sc.x]; }
        else { sc.x = 0; sc.y = 0x7fffffff; sc.z = 0; }
        sc.w = 0;
        g_sched[i] = sc;
    }
    if (tid == 0) { g_S0 = S0; g_T = istar; g_P = P; }

    // ---- phase-B per-node counts + offsets (scan 3)
    if (tid < NN) s_cnt[tid] = 0;
    __syncthreads();
    for (int i = P + tid; i < istar; i += 1024) atomicAdd(&s_cnt[s_nx[i]], 1);
    __syncthreads();
    const int cnt0 = (tid < NN) ? s_cnt[tid] : 0;
    scanbuf[0][tid] = cnt0;
    __syncthreads();
    src = 0;
    for (int off = 1; off < 1024; off <<= 1) {
        int v = scanbuf[src][tid];
        if (tid >= off) v += scanbuf[src][tid - off];
        scanbuf[src ^ 1][tid] = v;
        src ^= 1;
        __syncthreads();
    }
    if (tid <= NN) g_noff[tid] = scanbuf[src][tid] - ((tid < NN) ? cnt0 : 0);

    // ---- counting sort of phase-B nodes by chain length (descending)
    if (tid < 64) s_hist[tid] = 0;
    __syncthreads();
    if (tid < NN && cnt0 > 0) atomicAdd(&s_hist[(cnt0 < 63) ? cnt0 : 63], 1);
    __syncthreads();
    if (tid == 0) {
        int acc = 0;
        for (int b = 63; b >= 1; --b) { const int t = s_hist[b]; s_hist[b] = acc; acc += t; }
        g_nB = acc;
    }
    __syncthreads();
    if (tid < NN && cnt0 > 0) {
        const int p = atomicAdd(&s_hist[(cnt0 < 63) ? cnt0 : 63], 1);
        g_border[p] = tid;
    }
    if (tid < NCLUS * WPC) g_tflag[tid >> 3][tid & 7] = -1;

    for (int i = tid; i < MAX_STEPS; i += 1024) g_mready[i] = (i < S0) ? 1 : 0;
}

// ---------------- lists + qinit: nlist | alist | initial messages ----------------
__global__ __launch_bounds__(256) void k_lists2(const float* __restrict__ first_message) {
    __shared__ int sWOff[4];
    __shared__ int sBase;
    const int b = blockIdx.x, tid = threadIdx.x;
    const int lane = tid & 63, wv = tid >> 6;
    if (b < NN) {
        const int v = b;
        const int lo = g_P, hi = g_T;
        if (tid == 0) sBase = g_noff[v];
        __syncthreads();
        for (int st = lo; st < hi; st += 256) {
            const int i = st + tid;
            const bool m = (i < hi) && (g_sched[i].x == v);
            const unsigned long long bal = __ballot(m);
            const int rank = __popcll(bal & ((1ull << lane) - 1ull));
            if (lane == 0) sWOff[wv] = __popcll(bal);
            __syncthreads();
            if (tid == 0) {
                int acc = sBase;
                for (int w = 0; w < 4; ++w) { const int t = sWOff[w]; sWOff[w] = acc; acc += t; }
                sBase = acc;
            }
            __syncthreads();
            if (m) g_nlist[sWOff[wv] + rank] = i;
            __syncthreads();
        }
    } else if (b < NN + NWGA) {
        const int w0 = b - NN;
        const int hi = g_P;
        if (tid == 0) sBase = 0;
        __syncthreads();
        for (int st = 0; st < hi; st += 256) {
            const int i = st + tid;
            const bool m = (i < hi) && ((g_sched[i].x & (NWGA - 1)) == w0);
            const unsigned long long bal = __ballot(m);
            const int rank = __popcll(bal & ((1ull << lane) - 1ull));
            if (lane == 0) sWOff[wv] = __popcll(bal);
            __syncthreads();
            if (tid == 0) {
                int acc = sBase;
                for (int w = 0; w < 4; ++w) { const int t = sWOff[w]; sWOff[w] = acc; acc += t; }
                sBase = acc;
            }
            __syncthreads();
            if (m) g_alist[w0][sWOff[wv] + rank] = i;
            __syncthreads();
        }
        if (tid == 0) g_acnt[w0] = sBase;
    } else {                       // qinit: 2 steps per block
        const int i = (b - NN - NWGA) * 2 + (tid >> 7);
        const int col = tid & 127;
        if (i < g_S0) g_qmsgs[i][col] = first_message[g_sched[i].x * MSGD + col];
    }
}

// ---------------- phase A: dataflow with hh-matvec overlapped under msg wait ----------------
__global__ __launch_bounds__(512, 1) void k_phaseA(const float* __restrict__ nm_b) {
    __shared__ float sAct[MSGD];
    __shared__ float sNH[2][HID], sNC[2][HID];
    __shared__ float sGates[1024];
    __shared__ float sPart[4 * MSGD];
    __shared__ unsigned int sActP[192];    // gate acts packed: [msg(64) | h(128)] pairs
    __shared__ unsigned int sActN[192];    // nm acts packed:   [h(128) | msg(64)] pairs
    const int tid = threadIdx.x, wg = blockIdx.x;
    const int cntA = g_acnt[wg];
    if (cntA == 0) return;
    const int S0 = g_S0, T = g_T;
    const float vb0 = g_bias[2 * tid], vb1 = g_bias[2 * tid + 1];
    const uint4* wp = g_WTph + tid;

    for (int idx = tid; idx < 2 * HID; idx += 512) {
        int sl = idx >> 8, u = idx & 255, v = wg + (sl << 8);
        sNH[sl][u] = g_hid[v][u];
        sNC[sl][u] = g_cell[v][u];
    }
    __syncthreads();

    for (int k = 0; k < cntA; ++k) {
        const int s = g_alist[wg][k];
        const int4 sc = g_sched[s];
        const int node = sc.x, y = sc.y, deg = sc.z, sl = node >> 8;

        // pack h_prev pairs (stable since previous step's barriers) — msg-independent
        if (tid >= 64 && tid < 192) {
            const int jx = tid - 64;
            sActP[tid] = pkh(sNH[sl][2 * jx], sNH[sl][2 * jx + 1]);
        }
        __syncthreads();

        // hh-part matvec (quads 32..95) — executes under the message wait
        float acc0 = vb0, acc1 = vb1;
        {
            const uint4* wph = wp + 32 * 512;
            uint4 wA[8], wB[8];
#pragma unroll
            for (int j = 0; j < 8; ++j) wA[j] = wph[j * 512];
#pragma unroll
            for (int j = 0; j < 8; ++j) wB[j] = wph[(8 + j) * 512];
#pragma unroll 1
            for (int qb = 0; qb < 64; qb += 16) {
#pragma unroll
                for (int j = 0; j < 8; ++j) {
                    const int q = 32 + qb + j;
                    const unsigned int a01 = sActP[2 * q], a23 = sActP[2 * q + 1];
                    acc0 = fdot2u(wA[j].x, a01, acc0); acc1 = fdot2u(wA[j].y, a01, acc1);
                    acc0 = fdot2u(wA[j].z, a23, acc0); acc1 = fdot2u(wA[j].w, a23, acc1);
                }
#pragma unroll
                for (int j = 0; j < 8; ++j) wA[j] = wph[(qb + 16 + j) * 512];   // pad-safe
#pragma unroll
                for (int j = 0; j < 8; ++j) {
                    const int q = 32 + qb + 8 + j;
                    const unsigned int a01 = sActP[2 * q], a23 = sActP[2 * q + 1];
                    acc0 = fdot2u(wB[j].x, a01, acc0); acc1 = fdot2u(wB[j].y, a01, acc1);
                    acc0 = fdot2u(wB[j].z, a23, acc0); acc1 = fdot2u(wB[j].w, a23, acc1);
                }
#pragma unroll
                for (int j = 0; j < 8; ++j) wB[j] = wph[(qb + 24 + j) * 512];   // pad-safe
            }
        }

        // now wait for the message (most of this wait was covered by the hh work)
        if (s >= S0) {
            if (tid == 0) {
                while (__hip_atomic_load(&g_mready[s], __ATOMIC_RELAXED,
                                         __HIP_MEMORY_SCOPE_AGENT) == 0)
                    __builtin_amdgcn_s_sleep(2);
            }
            __syncthreads();
            __builtin_amdgcn_fence(__ATOMIC_ACQUIRE, "workgroup");
        }
        // stage message + pack
        if (tid < 64) {
            float a0, a1;
            if (s < S0) { a0 = g_qmsgs[s][2 * tid]; a1 = g_qmsgs[s][2 * tid + 1]; }
            else {
                a0 = __hip_atomic_load(&g_qmsgs[s][2 * tid],     __ATOMIC_RELAXED,
                                       __HIP_MEMORY_SCOPE_AGENT);
                a1 = __hip_atomic_load(&g_qmsgs[s][2 * tid + 1], __ATOMIC_RELAXED,
                                       __HIP_MEMORY_SCOPE_AGENT);
            }
            sAct[2 * tid] = a0; sAct[2 * tid + 1] = a1;
            sActP[tid] = pkh(a0, a1);
        }
        __syncthreads();
        // ih-part matvec (quads 0..31) accumulates onto the hh partials
        {
            uint4 wA[8], wB[8];
#pragma unroll
            for (int j = 0; j < 8; ++j) wA[j] = wp[j * 512];
#pragma unroll
            for (int j = 0; j < 8; ++j) wB[j] = wp[(8 + j) * 512];
#pragma unroll 1
            for (int qb = 0; qb < 32; qb += 16) {
#pragma unroll
                for (int j = 0; j < 8; ++j) {
                    const int q = qb + j;
                    const unsigned int a01 = sActP[2 * q], a23 = sActP[2 * q + 1];
                    acc0 = fdot2u(wA[j].x, a01, acc0); acc1 = fdot2u(wA[j].y, a01, acc1);
                    acc0 = fdot2u(wA[j].z, a23, acc0); acc1 = fdot2u(wA[j].w, a23, acc1);
                }
#pragma unroll
                for (int j = 0; j < 8; ++j) wA[j] = wp[(qb + 16 + j) * 512];   // pad-safe
#pragma unroll
                for (int j = 0; j < 8; ++j) {
                    const int q = qb + 8 + j;
                    const unsigned int a01 = sActP[2 * q], a23 = sActP[2 * q + 1];
                    acc0 = fdot2u(wB[j].x, a01, acc0); acc1 = fdot2u(wB[j].y, a01, acc1);
                    acc0 = fdot2u(wB[j].z, a23, acc0); acc1 = fdot2u(wB[j].w, a23, acc1);
                }
#pragma unroll
                for (int j = 0; j < 8; ++j) wB[j] = wp[(qb + 24 + j) * 512];   // pad-safe
            }
            ((float2*)sGates)[tid] = make_float2(acc0, acc1);
        }
        __syncthreads();
        // LSTM cell (torch order i,f,g,o)
        if (tid < HID) {
            const int u = tid;
            const float gi = sGates[u], gf = sGates[256 + u];
            const float gg = sGates[512 + u], go = sGates[768 + u];
            const float cp = sNC[sl][u];
            const float cn = sigm(gf) * cp + sigm(gi) * tanhf(gg);
            const float hn = sigm(go) * tanhf(cn);
            sNC[sl][u] = cn;
            sNH[sl][u] = hn;
        }
        __syncthreads();
        // pack nm acts: [h_new(256) | msg(128)]
        if (tid < 128) sActN[tid] = pkh(sNH[sl][2 * tid], sNH[sl][2 * tid + 1]);
        else if (tid < 192) {
            const int j = tid - 128;
            sActN[tid] = pkh(sAct[2 * j], sAct[2 * j + 1]);
        }
        __syncthreads();
        // nm partials: o = tid&127, col-quarter cq = tid>>7 covers 48 pairs
        {
            const int o = tid & (MSGD - 1), cq = tid >> 7;
            float p = 0.0f;
#pragma unroll 8
            for (int j = 0; j < 48; ++j) {
                const int cp = 48 * cq + j;
                p = fdot2u(g_nmTph[cp * 128 + o], sActN[cp], p);
            }
            sPart[cq * MSGD + o] = p;
        }
        __syncthreads();
        const int lim = (y + deg <= T) ? deg : (T - y);
        if (tid < MSGD) {
            const float m = nm_b[tid] + sPart[tid] + sPart[MSGD + tid]
                          + sPart[2 * MSGD + tid] + sPart[3 * MSGD + tid];
            const float mN = __shfl_down(m, 1);      // pair partner (same wave)
            for (int e = 0; e < lim; ++e)
                __hip_atomic_store(&g_qmsgs[y + e][tid], m, __ATOMIC_RELAXED,
                                   __HIP_MEMORY_SCOPE_AGENT);
            if ((tid & 1) == 0) {                    // f16-packed copy for phase B
                const unsigned int pm = pkh(m, mN);  // (plain store: kernel-boundary vis.)
                unsigned int* pd = (unsigned int*)g_qmsgP4;
                for (int e = 0; e < lim; ++e) pd[(y + e) * 64 + (tid >> 1)] = pm;
            }
        }
        __syncthreads();   // drain all waves' stores before flags
        if (tid < lim)
            __hip_atomic_store(&g_mready[y + tid], 1, __ATOMIC_RELAXED,
                               __HIP_MEMORY_SCOPE_AGENT);
    }
    __syncthreads();
    for (int idx = tid; idx < 2 * HID; idx += 512) {
        int sl = idx >> 8, u = idx & 255, v = wg + (sl << 8);
        g_hid[v][u]  = sNH[sl][u];
        g_cell[v][u] = sNC[sl][u];
    }
}

// ---------------- phase B: MFMA 8-WG clusters (r20) + poll/msg-stage overlap ----------------
__global__ __launch_bounds__(512, 1) void k_phaseB() {
    __shared__ uint4 sB[12 * 64];          // B fragments [ktile][lane]
    __shared__ float sG[128][17];          // gates [local row][slot]
    __shared__ float sC[KSLOT][32];        // cell slices (own units)
    __shared__ int sNode[KSLOT], sLen[KSLOT], sOff[KSLOT], sStep[KSLOT];
    __shared__ int sMaxLen;
    const int tid = threadIdx.x, wg = blockIdx.x;
    const int c = wg >> 3, j = wg & 7;
    const int wv = tid >> 6, lane = tid & 63;
    const int nB = g_nB;

    if (tid < KSLOT) {
        const int ci = tid * NCLUS + c;
        if (ci < nB) {
            const int v = g_border[ci];
            sNode[tid] = v;
            sOff[tid]  = g_noff[v];
            sLen[tid]  = g_noff[v + 1] - g_noff[v];
        } else { sNode[tid] = -1; sLen[tid] = 0; sOff[tid] = 0; }
    }
    if (tid == 0) sMaxLen = 0;
    __syncthreads();
    if (tid < KSLOT) atomicMax(&sMaxLen, sLen[tid]);
    __syncthreads();
    const int maxlen = sMaxLen;
    if (maxlen == 0) return;

    // zero B fragments (inactive slots stay finite)
    {
        uint4 z; z.x = z.y = z.z = z.w = 0u;
        for (int i = tid; i < 12 * 64; i += 512) sB[i] = z;
    }
    // A fragments -> VGPRs (12 x f16x8 = 48 VGPRs, loop-invariant; proven resident)
    f16x8 afr[12];
    {
        const f16x8* src = (const f16x8*)g_WBm + ((j * 8 + wv) * 12) * 64 + lane;
#pragma unroll
        for (int kt = 0; kt < 12; ++kt) afr[kt] = src[kt * 64];
    }
    // per-lane accumulator bias: rows rl = 16wv + (lane>>4)*4 + r
    f32x4 bias;
#pragma unroll
    for (int r = 0; r < 4; ++r) {
        const int rl = 16 * wv + (lane >> 4) * 4 + r;
        bias[r] = g_bias[(rl >> 5) * 256 + (j << 5) + (rl & 31)];
    }
    // prologue: load cell; pack + publish initial h (own 32-unit slice) to buffer 1
    {
        const int k = tid >> 5, u = tid & 31;
        if (sNode[k] >= 0) sC[k][u] = g_cell[sNode[k]][(j << 5) + u];
    }
    for (int idx = tid; idx < KSLOT * 16; idx += 512) {
        const int k = idx >> 4, d = idx & 15;
        if (sNode[k] >= 0) {
            const float h0 = g_hid[sNode[k]][(j << 5) + 2 * d];
            const float h1 = g_hid[sNode[k]][(j << 5) + 2 * d + 1];
            __hip_atomic_store((unsigned int*)g_hpk4[1][sNode[k]] + (j << 4) + d,
                               pkh(h0, h1), __ATOMIC_RELAXED, __HIP_MEMORY_SCOPE_AGENT);
        }
    }
    __syncthreads();
    if (tid == 0)
        __hip_atomic_store(&g_tflag[c][j], 0, __ATOMIC_RELAXED, __HIP_MEMORY_SCOPE_AGENT);

    for (int tick = 0; tick < maxlen; ++tick) {
        if (tid < KSLOT) sStep[tid] = (tick < sLen[tid]) ? g_nlist[sOff[tid] + tick] : -1;
        __syncthreads();
        // stage msg quads (kt<4, flag-independent) while threads 0..7 poll flags
        for (int idx = tid; idx < 4 * 64; idx += 512) {
            const int l = idx & 63, kt = idx >> 6;
            const int n = l & 15, s = sStep[n];
            if (s >= 0) sB[kt * 64 + l] = g_qmsgP4[s][kt * 4 + (l >> 4)];
        }
        if (tid < WPC) {
            while (__hip_atomic_load(&g_tflag[c][tid], __ATOMIC_RELAXED,
                                     __HIP_MEMORY_SCOPE_AGENT) < tick)
                __builtin_amdgcn_s_sleep(1);
        }
        __syncthreads();
        // stage h quads (kt 4..11) from parity buffer (flags now >= tick)
        const int pb = (tick + 1) & 1;     // h from tick-1 lives in buffer (tick-1)&1
        for (int idx = tid; idx < 8 * 64; idx += 512) {
            const int l = idx & 63, kt = 4 + (idx >> 6);
            const int n = l & 15, s = sStep[n];
            if (s >= 0) {
                const int g = kt * 4 + (l >> 4) - 16;
                const unsigned long long* hp =
                    (const unsigned long long*)g_hpk4[pb][sNode[n]];
                const unsigned long long lo = __hip_atomic_load(
                    hp + g * 2, __ATOMIC_RELAXED, __HIP_MEMORY_SCOPE_AGENT);
                const unsigned long long hi = __hip_atomic_load(
                    hp + g * 2 + 1, __ATOMIC_RELAXED, __HIP_MEMORY_SCOPE_AGENT);
                uint4 val;
                val.x = (unsigned int)lo; val.y = (unsigned int)(lo >> 32);
                val.z = (unsigned int)hi; val.w = (unsigned int)(hi >> 32);
                sB[kt * 64 + l] = val;
            }
        }
        __syncthreads();
        // 12 MFMAs: D[row][slot] = sum_k W[row][k] * act[slot][k] + bias
        {
            f32x4 acc = bias;
#pragma unroll
            for (int kt = 0; kt < 12; ++kt) {
                const f16x8 bfr = ((const f16x8*)sB)[kt * 64 + lane];
                acc = __builtin_amdgcn_mfma_f32_16x16x32_f16(afr[kt], bfr, acc, 0, 0, 0);
            }
            const int n = lane & 15, rbase = 16 * wv + (lane >> 4) * 4;
#pragma unroll
            for (int r = 0; r < 4; ++r) sG[rbase + r][n] = acc[r];
        }
        __syncthreads();
        // cell update + packed h publish (torch gate order i,f,g,o)
        {
            const int k = tid >> 5, u = tid & 31;
            const int v = sNode[k];
            const bool act = (sStep[k] >= 0);
            float hn = 0.0f;
            if (act) {
                const float gi = sG[u][k],      gf = sG[32 + u][k];
                const float gg = sG[64 + u][k], go = sG[96 + u][k];
                const float cn = sigm(gf) * sC[k][u] + sigm(gi) * tanhf(gg);
                sC[k][u] = cn;
                hn = sigm(go) * tanhf(cn);
            }
            const float hn1 = __shfl_down(hn, 1);
            if (act) {
                if ((u & 1) == 0) {
                    unsigned int* dst = (unsigned int*)g_hpk4[tick & 1][v];
                    __hip_atomic_store(&dst[(j << 4) + (u >> 1)], pkh(hn, hn1),
                                       __ATOMIC_RELAXED, __HIP_MEMORY_SCOPE_AGENT);
                }
                if (tick == sLen[k] - 1) g_hid[v][(j << 5) + u] = hn;  // final f32 for decoder
            }
        }
        __syncthreads();   // drain all waves' h stores before flag
        if (tid == 0)
            __hip_atomic_store(&g_tflag[c][j], tick + 1, __ATOMIC_RELAXED,
                               __HIP_MEMORY_SCOPE_AGENT);
    }
}

// ---------------- decoder: logits + log_softmax ----------------
__global__ __launch_bounds__(256) void k_decode(const float* __restrict__ dec_W,
                                                const float* __restrict__ dec_b,
                                                float* __restrict__ out) {
    const int gtid = blockIdx.x * 256 + threadIdx.x;
    const int row = gtid >> 4, lane = gtid & 15;   // row = p*NN + n
    const int p = row >> 9, n = row & (NN - 1);
    const float* dw = dec_W + (p * OUTC + lane) * HID;
    float acc = dec_b[p * OUTC + lane];
#pragma unroll 8
    for (int j = 0; j < HID; j += 4) {
        const float4 hv = *(const float4*)&g_hid[n][j];
        const float4 wv = *(const float4*)(dw + j);
        acc += hv.x * wv.x + hv.y * wv.y + hv.z * wv.z + hv.w * wv.w;
    }
    float mx = acc;
    mx = fmaxf(mx, __shfl_xor(mx, 1));
    mx = fmaxf(mx, __shfl_xor(mx, 2));
    mx = fmaxf(mx, __shfl_xor(mx, 4));
    mx = fmaxf(mx, __shfl_xor(mx, 8));
    float s = expf(acc - mx);
    s += __shfl_xor(s, 1);
    s += __shfl_xor(s, 2);
    s += __shfl_xor(s, 4);
    s += __shfl_xor(s, 8);
    out[row * OUTC + lane] = acc - mx - logf(s);
}

extern "C" void kernel_launch(void* const* d_in, const int* in_sizes, int n_in,
                              void* d_out, int out_size, void* d_ws, size_t ws_size,
                              hipStream_t stream) {
    (void)in_sizes; (void)n_in; (void)out_size; (void)d_ws; (void)ws_size;
    const float* xa   = (const float*)d_in[0];
    const float* fm   = (const float*)d_in[1];
    const int*   ei   = (const int*)d_in[2];
    const int*   st   = (const int*)d_in[3];
    const float* encW = (const float*)d_in[4];
    const float* encb = (const float*)d_in[5];
    const float* Wih  = (const float*)d_in[6];
    const float* Whh  = (const float*)d_in[7];
    const float* bih  = (const float*)d_in[8];
    const float* bhh  = (const float*)d_in[9];
    const float* nmW  = (const float*)d_in[10];
    const float* nmb  = (const float*)d_in[11];
    const float* decW = (const float*)d_in[12];
    const float* decb = (const float*)d_in[13];
    float* out = (float*)d_out;

    hipLaunchKernelGGL(k_setup,  dim3(1728),            dim3(256),  0, stream,
                       xa, encW, encb, Wih, Whh, bih, bhh, nmW, ei);
    hipLaunchKernelGGL(k_sched,  dim3(1),               dim3(1024), 0, stream, st);
    hipLaunchKernelGGL(k_lists2, dim3(NN + NWGA + 256), dim3(256),  0, stream, fm);
    hipLaunchKernelGGL(k_phaseA, dim3(NWGA),            dim3(512),  0, stream, nmb);
    hipLaunchKernelGGL(k_phaseB, dim3(NCLUS * WPC),     dim3(512),  0, stream);
    hipLaunchKernelGGL(k_decode, dim3(128),             dim3(256),  0, stream, decW, decb, out);
}

// Round 22
// 216.450 us; speedup vs baseline: 1.4478x; 1.4478x over previous
//
#include <hip/hip_runtime.h>
#include <math.h>

// ---------------- problem constants ----------------
#define NN 512
#define EE 2048
#define IN_F 64
#define HID 256
#define MSGD 128
#define OUTC 16
#define MAX_STEPS 5120

// ---------------- kernel config ----------------
#define NWGA 256      // phase-A WGs (node & 255 ownership)
#define MAXD 64       // padded neighbor-row stride
#define NCLUS 32      // phase-B clusters
#define WPC 8         // phase-B WGs per cluster (32 units x 4 gates = 128 rows each)
#define KSLOT 16      // chain slots per cluster

typedef _Float16 h2v __attribute__((ext_vector_type(2)));
typedef _Float16 f16x8 __attribute__((ext_vector_type(8)));
typedef float f32x4 __attribute__((ext_vector_type(4)));

static __device__ __forceinline__ float fdot2u(unsigned int w, unsigned int a, float c) {
    return __builtin_amdgcn_fdot2(__builtin_bit_cast(h2v, w),
                                  __builtin_bit_cast(h2v, a), c, false);
}
static __device__ __forceinline__ unsigned int pkh(float a, float b) {
    h2v h; h.x = (_Float16)a; h.y = (_Float16)b;     // RTN converts
    return __builtin_bit_cast(unsigned int, h);
}

// ---------------- device globals (all rewritten every call) ----------------
__device__ int   g_nbrs64[NN][MAXD];
__device__ int   g_degs[NN];
__device__ int4  g_sched[MAX_STEPS];     // x=node, y=t(enqueue base), z=deg
__device__ int   g_mready[MAX_STEPS];
__device__ int   g_S0, g_T, g_P;
__device__ int   g_alist[NWGA][MAX_STEPS];
__device__ int   g_acnt[NWGA];
__device__ int   g_noff[NN + 1];
__device__ int   g_nlist[MAX_STEPS];     // phase-B steps grouped by node
__device__ int   g_border[NN];           // phase-B nodes sorted by chain length desc
__device__ int   g_nB;
__device__ int   g_tflag[NCLUS][WPC];    // per-cluster per-WG tick flags (init -1)
__device__ float g_qmsgs[MAX_STEPS][MSGD];
__device__ uint4 g_qmsgP4[MAX_STEPS][16];   // f16-packed messages (phase-B consumed)
__device__ uint4 g_hpk4[2][NN][32];         // f16-packed h, tick-parity double buffer
__device__ float g_hid[NN][HID];
__device__ float g_cell[NN][HID];
__device__ uint4 g_WTph[112 * 512];      // f16-packed gates [colquad q][rowpair r] (phase A)
__device__ uint4 g_WBm[WPC * 8 * 12 * 64]; // phase-B MFMA A-frags [j][wave][kt][lane]
__device__ unsigned int g_nmTph[192 * 128]; // f16-packed nm: [colpair cp][out o]
__device__ float g_bias[1024];           // b_ih + b_hh

__device__ __forceinline__ float sigm(float x) { return 1.0f / (1.0f + expf(-x)); }
__device__ __forceinline__ float gw(const float* W_ih, const float* W_hh, int row, int c) {
    return (c < MSGD) ? W_ih[row * MSGD + c] : W_hh[row * HID + (c - MSGD)];
}

// ---------------- fused setup: encoder | phase-A weight pack | phase-B frags | nbr ----------------
__global__ __launch_bounds__(256) void k_setup(const float* __restrict__ xa,
                                               const float* __restrict__ enc_W,
                                               const float* __restrict__ enc_b,
                                               const float* __restrict__ W_ih,
                                               const float* __restrict__ W_hh,
                                               const float* __restrict__ b_ih,
                                               const float* __restrict__ b_hh,
                                               const float* __restrict__ nm_W,
                                               const int* __restrict__ edge_index) {
    const int b = blockIdx.x, tid = threadIdx.x;
    if (b < 512) {                 // encoder: hid = xa @ enc_W^T + enc_b; cell = 0
        const int gid = b * 256 + tid;
        const int n = gid >> 8, ccol = gid & 255;
        const float* x = xa + n * IN_F;
        const float* w = enc_W + ccol * IN_F;
        float acc = enc_b[ccol];
#pragma unroll 8
        for (int j = 0; j < IN_F; ++j) acc += x[j] * w[j];
        g_hid[n][ccol] = acc;
        g_cell[n][ccol] = 0.0f;
    } else if (b < 1024) {         // phase-A weight pack (row-pair r)
        const int r = b - 512;
        for (int q = tid; q < 96; q += 256) {
            uint4 v;
            v.x = pkh(gw(W_ih, W_hh, 2 * r, 4 * q),     gw(W_ih, W_hh, 2 * r, 4 * q + 1));
            v.y = pkh(gw(W_ih, W_hh, 2 * r + 1, 4 * q), gw(W_ih, W_hh, 2 * r + 1, 4 * q + 1));
            v.z = pkh(gw(W_ih, W_hh, 2 * r, 4 * q + 2), gw(W_ih, W_hh, 2 * r, 4 * q + 3));
            v.w = pkh(gw(W_ih, W_hh, 2 * r + 1, 4 * q + 2), gw(W_ih, W_hh, 2 * r + 1, 4 * q + 3));
            g_WTph[q * 512 + r] = v;
        }
        if (r < 192 && tid < 128)
            g_nmTph[r * 128 + tid] = pkh(nm_W[tid * 384 + 2 * r], nm_W[tid * 384 + 2 * r + 1]);
        if (r == 0)
            for (int g = tid; g < 1024; g += 256) g_bias[g] = b_ih[g] + b_hh[g];
    } else if (b < 1216) {         // phase-B MFMA A-fragments (4 frag-blocks per block)
        const int b4 = (b - 1024) * 4 + (tid >> 6);   // 0..767 = (j, wave, kt)
        const int lane = tid & 63;
        const int j = b4 / 96, rem = b4 - j * 96;
        const int w = rem / 12, kt = rem - w * 12;
        const int rl = 16 * w + (lane & 15);
        const int R = (rl >> 5) * 256 + (j << 5) + (rl & 31);
        const int kb = kt * 32 + (lane >> 4) * 8;
        unsigned int d[4];
#pragma unroll
        for (int q = 0; q < 4; ++q)
            d[q] = pkh(gw(W_ih, W_hh, R, kb + 2 * q), gw(W_ih, W_hh, R, kb + 2 * q + 1));
        uint4 v; v.x = d[0]; v.y = d[1]; v.z = d[2]; v.w = d[3];
        g_WBm[b4 * 64 + lane] = v;
    } else {                        // neighbor lists (node v)
        __shared__ unsigned int bits[16];
        const int v = b - 1216;
        if (tid < 16) bits[tid] = 0u;
        __syncthreads();
        for (int e = tid; e < EE; e += 256) {
            const int s = edge_index[e], d = edge_index[EE + e];
            if (s == v) atomicOr(&bits[d >> 5], 1u << (d & 31));
            if (d == v) atomicOr(&bits[s >> 5], 1u << (s & 31));
        }
        __syncthreads();
        if (tid == 0) {
            int cnt = 0;
            for (int w = 0; w < 16; ++w) {
                unsigned int bb = bits[w];
                while (bb) {
                    const int j = __ffs(bb) - 1;
                    bb &= bb - 1u;
                    if (cnt < MAXD) g_nbrs64[v][cnt++] = w * 32 + j;
                }
            }
            g_degs[v] = cnt;
        }
    }
}

// ---------------- schedule expansion: single block, parallel scans ----------------
__global__ __launch_bounds__(1024) void k_sched(const int* __restrict__ starts) {
    __shared__ int s_nx[MAX_STEPS];
    __shared__ int s_ny[MAX_STEPS];
    __shared__ int scanbuf[2][1024];
    __shared__ int s_deg[NN];
    __shared__ int s_off[NN + 1];
    __shared__ int s_csr[4160];
    __shared__ int s_nodes[NN];
    __shared__ int s_cnt[NN];
    __shared__ int s_misc[4];
    __shared__ int s_hist[64];
    const int tid = threadIdx.x;

    const int stt = (tid < NN && starts[tid] != 0) ? 1 : 0;
    const int dg0 = (tid < NN) ? g_degs[tid] : 0;
    if (tid < NN) s_deg[tid] = dg0;
    for (int i = tid; i < MAX_STEPS; i += 1024) s_ny[i] = 0x7fffffff;

    // ---- scan 1: degree prefix -> s_off (CSR offsets)
    scanbuf[0][tid] = dg0;
    __syncthreads();
    int src = 0;
    for (int off = 1; off < 1024; off <<= 1) {
        int v = scanbuf[src][tid];
        if (tid >= off) v += scanbuf[src][tid - off];
        scanbuf[src ^ 1][tid] = v;
        src ^= 1;
        __syncthreads();
    }
    if (tid <= NN) s_off[tid] = scanbuf[src][tid] - ((tid < NN) ? dg0 : 0);
    __syncthreads();

    // ---- scan 2: start-node compaction -> s_nodes, S0
    scanbuf[0][tid] = stt;
    __syncthreads();
    src = 0;
    for (int off = 1; off < 1024; off <<= 1) {
        int v = scanbuf[src][tid];
        if (tid >= off) v += scanbuf[src][tid - off];
        scanbuf[src ^ 1][tid] = v;
        src ^= 1;
        __syncthreads();
    }
    if (stt) s_nodes[scanbuf[src][tid] - 1] = tid;
    const int S0tot = scanbuf[src][1023];
    __syncthreads();

    // ---- stage CSR into LDS; init queue head
    if (tid < NN) {
        const int o = s_off[tid], dg = s_deg[tid];
        for (int e = 0; e < dg; ++e) s_csr[o + e] = g_nbrs64[tid][e];
    }
    const int S0 = (S0tot < MAX_STEPS) ? S0tot : MAX_STEPS;
    int known = S0;
    for (int i = tid; i < known; i += 1024) s_nx[i] = s_nodes[i];
    __syncthreads();

    // ---- round-expansion (message-independent), all in LDS
    for (int round = 0; round < 8 && known > 0; ++round) {
        const int C = (known + 1023) >> 10;
        const int base = tid * C;
        int lsum = 0;
        for (int j = 0; j < C; ++j) {
            int i = base + j;
            if (i < known) lsum += s_deg[s_nx[i]];
        }
        scanbuf[0][tid] = lsum;
        __syncthreads();
        src = 0;
        for (int off = 1; off < 1024; off <<= 1) {
            int v = scanbuf[src][tid];
            if (tid >= off) v += scanbuf[src][tid - off];
            scanbuf[src ^ 1][tid] = v;
            src ^= 1;
            __syncthreads();
        }
        const int excl = (tid == 0) ? 0 : scanbuf[src][tid - 1];
        const int total = scanbuf[src][1023];
        int t = S0 + excl;
        for (int j = 0; j < C; ++j) {
            int i = base + j;
            if (i < known) {
                const int nd = s_nx[i];
                const int dg = s_deg[nd], o = s_off[nd];
                s_ny[i] = t;
                for (int e = 0; e < dg; ++e) {
                    const int pos = t + e;
                    if (pos >= known && pos < MAX_STEPS) s_nx[pos] = s_csr[o + e];
                }
                t += dg;
            }
        }
        __syncthreads();
        int newknown = S0 + total;
        if (newknown > MAX_STEPS) newknown = MAX_STEPS;
        if (newknown == known) break;
        known = newknown;
    }
    __syncthreads();
    const int kn = known;
    if (tid == 0) s_misc[1] = kn;
    __syncthreads();
    for (int i = tid; i < kn; i += 1024)
        if (s_ny[i] <= i) atomicMin(&s_misc[1], i);        // first drained step
    __syncthreads();
    const int istar = s_misc[1];
    if (tid == 0) s_misc[2] = istar;
    __syncthreads();
    for (int i = tid; i < istar; i += 1024)
        if (s_ny[i] >= istar) atomicMin(&s_misc[2], i);    // first nothing-consumed producer
    __syncthreads();
    const int P = s_misc[2];

    // ---- write schedule (coalesced int4)
    for (int i = tid; i < MAX_STEPS; i += 1024) {
        int4 sc;
        if (i < kn) { sc.x = s_nx[i]; sc.y = s_ny[i]; sc.z = s_deg[sc.x]; }
        else { sc.x = 0; sc.y = 0x7fffffff; sc.z = 0; }
        sc.w = 0;
        g_sched[i] = sc;
    }
    if (tid == 0) { g_S0 = S0; g_T = istar; g_P = P; }

    // ---- phase-B per-node counts + offsets (scan 3)
    if (tid < NN) s_cnt[tid] = 0;
    __syncthreads();
    for (int i = P + tid; i < istar; i += 1024) atomicAdd(&s_cnt[s_nx[i]], 1);
    __syncthreads();
    const int cnt0 = (tid < NN) ? s_cnt[tid] : 0;
    scanbuf[0][tid] = cnt0;
    __syncthreads();
    src = 0;
    for (int off = 1; off < 1024; off <<= 1) {
        int v = scanbuf[src][tid];
        if (tid >= off) v += scanbuf[src][tid - off];
        scanbuf[src ^ 1][tid] = v;
        src ^= 1;
        __syncthreads();
    }
    if (tid <= NN) g_noff[tid] = scanbuf[src][tid] - ((tid < NN) ? cnt0 : 0);

    // ---- counting sort of phase-B nodes by chain length (descending)
    if (tid < 64) s_hist[tid] = 0;
    __syncthreads();
    if (tid < NN && cnt0 > 0) atomicAdd(&s_hist[(cnt0 < 63) ? cnt0 : 63], 1);
    __syncthreads();
    if (tid == 0) {
        int acc = 0;
        for (int b = 63; b >= 1; --b) { const int t = s_hist[b]; s_hist[b] = acc; acc += t; }
        g_nB = acc;
    }
    __syncthreads();
    if (tid < NN && cnt0 > 0) {
        const int p = atomicAdd(&s_hist[(cnt0 < 63) ? cnt0 : 63], 1);
        g_border[p] = tid;
    }
    if (tid < NCLUS * WPC) g_tflag[tid >> 3][tid & 7] = -1;

    for (int i = tid; i < MAX_STEPS; i += 1024) g_mready[i] = (i < S0) ? 1 : 0;
}

// ---------------- lists + qinit: nlist | alist | initial messages ----------------
__global__ __launch_bounds__(256) void k_lists2(const float* __restrict__ first_message) {
    __shared__ int sWOff[4];
    __shared__ int sBase;
    const int b = blockIdx.x, tid = threadIdx.x;
    const int lane = tid & 63, wv = tid >> 6;
    if (b < NN) {
        const int v = b;
        const int lo = g_P, hi = g_T;
        if (tid == 0) sBase = g_noff[v];
        __syncthreads();
        for (int st = lo; st < hi; st += 256) {
            const int i = st + tid;
            const bool m = (i < hi) && (g_sched[i].x == v);
            const unsigned long long bal = __ballot(m);
            const int rank = __popcll(bal & ((1ull << lane) - 1ull));
            if (lane == 0) sWOff[wv] = __popcll(bal);
            __syncthreads();
            if (tid == 0) {
                int acc = sBase;
                for (int w = 0; w < 4; ++w) { const int t = sWOff[w]; sWOff[w] = acc; acc += t; }
                sBase = acc;
            }
            __syncthreads();
            if (m) g_nlist[sWOff[wv] + rank] = i;
            __syncthreads();
        }
    } else if (b < NN + NWGA) {
        const int w0 = b - NN;
        const int hi = g_P;
        if (tid == 0) sBase = 0;
        __syncthreads();
        for (int st = 0; st < hi; st += 256) {
            const int i = st + tid;
            const bool m = (i < hi) && ((g_sched[i].x & (NWGA - 1)) == w0);
            const unsigned long long bal = __ballot(m);
            const int rank = __popcll(bal & ((1ull << lane) - 1ull));
            if (lane == 0) sWOff[wv] = __popcll(bal);
            __syncthreads();
            if (tid == 0) {
                int acc = sBase;
                for (int w = 0; w < 4; ++w) { const int t = sWOff[w]; sWOff[w] = acc; acc += t; }
                sBase = acc;
            }
            __syncthreads();
            if (m) g_alist[w0][sWOff[wv] + rank] = i;
            __syncthreads();
        }
        if (tid == 0) g_acnt[w0] = sBase;
    } else {                       // qinit: 2 steps per block
        const int i = (b - NN - NWGA) * 2 + (tid >> 7);
        const int col = tid & 127;
        if (i < g_S0) g_qmsgs[i][col] = first_message[g_sched[i].x * MSGD + col];
    }
}

// ---------------- phase A: fence-free dataflow over steps [0, P) ----------------
__global__ __launch_bounds__(512, 1) void k_phaseA(const float* __restrict__ nm_b) {
    __shared__ float sAct[MSGD];
    __shared__ float sNH[2][HID], sNC[2][HID];
    __shared__ float sGates[1024];
    __shared__ float sPart[4 * MSGD];
    __shared__ unsigned int sActP[192];    // gate acts packed: [msg(64) | h(128)] pairs
    __shared__ unsigned int sActN[192];    // nm acts packed:   [h(128) | msg(64)] pairs
    const int tid = threadIdx.x, wg = blockIdx.x;
    const int cntA = g_acnt[wg];
    if (cntA == 0) return;
    const int S0 = g_S0, T = g_T;
    const float vb0 = g_bias[2 * tid], vb1 = g_bias[2 * tid + 1];
    const uint4* wp = g_WTph + tid;

    for (int idx = tid; idx < 2 * HID; idx += 512) {
        int sl = idx >> 8, u = idx & 255, v = wg + (sl << 8);
        sNH[sl][u] = g_hid[v][u];
        sNC[sl][u] = g_cell[v][u];
    }
    __syncthreads();

    for (int k = 0; k < cntA; ++k) {
        const int s = g_alist[wg][k];
        const int4 sc = g_sched[s];
        const int node = sc.x, y = sc.y, deg = sc.z, sl = node >> 8;
        if (s >= S0) {
            if (tid == 0) {
                while (__hip_atomic_load(&g_mready[s], __ATOMIC_RELAXED,
                                         __HIP_MEMORY_SCOPE_AGENT) == 0)
                    __builtin_amdgcn_s_sleep(2);
            }
            __syncthreads();
            __builtin_amdgcn_fence(__ATOMIC_ACQUIRE, "workgroup");
        }
        // stage message + pack; pack h_prev
        if (tid < 64) {
            float a0, a1;
            if (s < S0) { a0 = g_qmsgs[s][2 * tid]; a1 = g_qmsgs[s][2 * tid + 1]; }
            else {
                a0 = __hip_atomic_load(&g_qmsgs[s][2 * tid],     __ATOMIC_RELAXED,
                                       __HIP_MEMORY_SCOPE_AGENT);
                a1 = __hip_atomic_load(&g_qmsgs[s][2 * tid + 1], __ATOMIC_RELAXED,
                                       __HIP_MEMORY_SCOPE_AGENT);
            }
            sAct[2 * tid] = a0; sAct[2 * tid + 1] = a1;
            sActP[tid] = pkh(a0, a1);
        } else if (tid < 192) {
            const int j = tid - 64;
            sActP[tid] = pkh(sNH[sl][2 * j], sNH[sl][2 * j + 1]);
        }
        __syncthreads();
        // gates: rows (2t, 2t+1), double-buffered 8-deep weight prefetch
        {
            float acc0 = vb0, acc1 = vb1;
            uint4 wA[8], wB[8];
#pragma unroll
            for (int j = 0; j < 8; ++j) wA[j] = wp[j * 512];
#pragma unroll
            for (int j = 0; j < 8; ++j) wB[j] = wp[(8 + j) * 512];
#pragma unroll 1
            for (int qb = 0; qb < 96; qb += 16) {
#pragma unroll
                for (int j = 0; j < 8; ++j) {
                    const int q = qb + j;
                    const unsigned int a01 = sActP[2 * q], a23 = sActP[2 * q + 1];
                    acc0 = fdot2u(wA[j].x, a01, acc0); acc1 = fdot2u(wA[j].y, a01, acc1);
                    acc0 = fdot2u(wA[j].z, a23, acc0); acc1 = fdot2u(wA[j].w, a23, acc1);
                }
#pragma unroll
                for (int j = 0; j < 8; ++j) wA[j] = wp[(qb + 16 + j) * 512];   // pad-safe
#pragma unroll
                for (int j = 0; j < 8; ++j) {
                    const int q = qb + 8 + j;
                    const unsigned int a01 = sActP[2 * q], a23 = sActP[2 * q + 1];
                    acc0 = fdot2u(wB[j].x, a01, acc0); acc1 = fdot2u(wB[j].y, a01, acc1);
                    acc0 = fdot2u(wB[j].z, a23, acc0); acc1 = fdot2u(wB[j].w, a23, acc1);
                }
#pragma unroll
                for (int j = 0; j < 8; ++j) wB[j] = wp[(qb + 24 + j) * 512];   // pad-safe
            }
            ((float2*)sGates)[tid] = make_float2(acc0, acc1);
        }
        __syncthreads();
        // LSTM cell (torch order i,f,g,o)
        if (tid < HID) {
            const int u = tid;
            const float gi = sGates[u], gf = sGates[256 + u];
            const float gg = sGates[512 + u], go = sGates[768 + u];
            const float cp = sNC[sl][u];
            const float cn = sigm(gf) * cp + sigm(gi) * tanhf(gg);
            const float hn = sigm(go) * tanhf(cn);
            sNC[sl][u] = cn;
            sNH[sl][u] = hn;
        }
        __syncthreads();
        // pack nm acts: [h_new(256) | msg(128)]
        if (tid < 128) sActN[tid] = pkh(sNH[sl][2 * tid], sNH[sl][2 * tid + 1]);
        else if (tid < 192) {
            const int j = tid - 128;
            sActN[tid] = pkh(sAct[2 * j], sAct[2 * j + 1]);
        }
        __syncthreads();
        // nm partials: o = tid&127, col-quarter cq = tid>>7 covers 48 pairs
        {
            const int o = tid & (MSGD - 1), cq = tid >> 7;
            float p = 0.0f;
#pragma unroll 8
            for (int j = 0; j < 48; ++j) {
                const int cp = 48 * cq + j;
                p = fdot2u(g_nmTph[cp * 128 + o], sActN[cp], p);
            }
            sPart[cq * MSGD + o] = p;
        }
        __syncthreads();
        const int lim = (y + deg <= T) ? deg : (T - y);
        if (tid < MSGD) {
            const float m = nm_b[tid] + sPart[tid] + sPart[MSGD + tid]
                          + sPart[2 * MSGD + tid] + sPart[3 * MSGD + tid];
            const float mN = __shfl_down(m, 1);      // pair partner (same wave)
            for (int e = 0; e < lim; ++e)
                __hip_atomic_store(&g_qmsgs[y + e][tid], m, __ATOMIC_RELAXED,
                                   __HIP_MEMORY_SCOPE_AGENT);
            if ((tid & 1) == 0) {                    // f16-packed copy for phase B
                const unsigned int pm = pkh(m, mN);  // (plain store: kernel-boundary vis.)
                unsigned int* pd = (unsigned int*)g_qmsgP4;
                for (int e = 0; e < lim; ++e) pd[(y + e) * 64 + (tid >> 1)] = pm;
            }
        }
        __syncthreads();   // drain all waves' stores before flags
        if (tid < lim)
            __hip_atomic_store(&g_mready[y + tid], 1, __ATOMIC_RELAXED,
                               __HIP_MEMORY_SCOPE_AGENT);
    }
    __syncthreads();
    for (int idx = tid; idx < 2 * HID; idx += 512) {
        int sl = idx >> 8, u = idx & 255, v = wg + (sl << 8);
        g_hid[v][u]  = sNH[sl][u];
        g_cell[v][u] = sNC[sl][u];
    }
}

// ---------------- phase B: MFMA 8-WG clusters + poll/msg-stage overlap ----------------
// 32 clusters x 8 WGs(512 thr); WG j owns 32 units x 4 gates = 128 rows; wave owns 16
// rows x 12 ktiles = 12 A-frags (48 VGPRs, proven resident). Per tick per wave: 12 MFMAs.
// Msg quads (kt<4, static) staged concurrently with the flag poll; h quads after.
__global__ __launch_bounds__(512, 1) void k_phaseB() {
    __shared__ uint4 sB[12 * 64];          // B fragments [ktile][lane]
    __shared__ float sG[128][17];          // gates [local row][slot]
    __shared__ float sC[KSLOT][32];        // cell slices (own units)
    __shared__ int sNode[KSLOT], sLen[KSLOT], sOff[KSLOT], sStep[KSLOT];
    __shared__ int sMaxLen;
    const int tid = threadIdx.x, wg = blockIdx.x;
    const int c = wg >> 3, j = wg & 7;
    const int wv = tid >> 6, lane = tid & 63;
    const int nB = g_nB;

    if (tid < KSLOT) {
        const int ci = tid * NCLUS + c;
        if (ci < nB) {
            const int v = g_border[ci];
            sNode[tid] = v;
            sOff[tid]  = g_noff[v];
            sLen[tid]  = g_noff[v + 1] - g_noff[v];
        } else { sNode[tid] = -1; sLen[tid] = 0; sOff[tid] = 0; }
    }
    if (tid == 0) sMaxLen = 0;
    __syncthreads();
    if (tid < KSLOT) atomicMax(&sMaxLen, sLen[tid]);
    __syncthreads();
    const int maxlen = sMaxLen;
    if (maxlen == 0) return;

    // zero B fragments (inactive slots stay finite)
    {
        uint4 z; z.x = z.y = z.z = z.w = 0u;
        for (int i = tid; i < 12 * 64; i += 512) sB[i] = z;
    }
    // A fragments -> VGPRs (12 x f16x8 = 48 VGPRs, loop-invariant; proven resident)
    f16x8 afr[12];
    {
        const f16x8* src = (const f16x8*)g_WBm + ((j * 8 + wv) * 12) * 64 + lane;
#pragma unroll
        for (int kt = 0; kt < 12; ++kt) afr[kt] = src[kt * 64];
    }
    // per-lane accumulator bias: rows rl = 16wv + (lane>>4)*4 + r
    f32x4 bias;
#pragma unroll
    for (int r = 0; r < 4; ++r) {
        const int rl = 16 * wv + (lane >> 4) * 4 + r;
        bias[r] = g_bias[(rl >> 5) * 256 + (j << 5) + (rl & 31)];
    }
    // prologue: load cell; pack + publish initial h (own 32-unit slice) to buffer 1
    {
        const int k = tid >> 5, u = tid & 31;
        if (sNode[k] >= 0) sC[k][u] = g_cell[sNode[k]][(j << 5) + u];
    }
    for (int idx = tid; idx < KSLOT * 16; idx += 512) {
        const int k = idx >> 4, d = idx & 15;
        if (sNode[k] >= 0) {
            const float h0 = g_hid[sNode[k]][(j << 5) + 2 * d];
            const float h1 = g_hid[sNode[k]][(j << 5) + 2 * d + 1];
            __hip_atomic_store((unsigned int*)g_hpk4[1][sNode[k]] + (j << 4) + d,
                               pkh(h0, h1), __ATOMIC_RELAXED, __HIP_MEMORY_SCOPE_AGENT);
        }
    }
    __syncthreads();
    if (tid == 0)
        __hip_atomic_store(&g_tflag[c][j], 0, __ATOMIC_RELAXED, __HIP_MEMORY_SCOPE_AGENT);

    for (int tick = 0; tick < maxlen; ++tick) {
        if (tid < KSLOT) sStep[tid] = (tick < sLen[tid]) ? g_nlist[sOff[tid] + tick] : -1;
        __syncthreads();
        // stage msg quads (kt<4, flag-independent) while threads 0..7 poll flags
        for (int idx = tid; idx < 4 * 64; idx += 512) {
            const int l = idx & 63, kt = idx >> 6;
            const int n = l & 15, s = sStep[n];
            if (s >= 0) sB[kt * 64 + l] = g_qmsgP4[s][kt * 4 + (l >> 4)];
        }
        if (tid < WPC) {
            while (__hip_atomic_load(&g_tflag[c][tid], __ATOMIC_RELAXED,
                                     __HIP_MEMORY_SCOPE_AGENT) < tick)
                __builtin_amdgcn_s_sleep(1);
        }
        __syncthreads();
        // stage h quads (kt 4..11) from parity buffer (flags now >= tick)
        const int pb = (tick + 1) & 1;     // h from tick-1 lives in buffer (tick-1)&1
        for (int idx = tid; idx < 8 * 64; idx += 512) {
            const int l = idx & 63, kt = 4 + (idx >> 6);
            const int n = l & 15, s = sStep[n];
            if (s >= 0) {
                const int g = kt * 4 + (l >> 4) - 16;
                const unsigned long long* hp =
                    (const unsigned long long*)g_hpk4[pb][sNode[n]];
                const unsigned long long lo = __hip_atomic_load(
                    hp + g * 2, __ATOMIC_RELAXED, __HIP_MEMORY_SCOPE_AGENT);
                const unsigned long long hi = __hip_atomic_load(
                    hp + g * 2 + 1, __ATOMIC_RELAXED, __HIP_MEMORY_SCOPE_AGENT);
                uint4 val;
                val.x = (unsigned int)lo; val.y = (unsigned int)(lo >> 32);
                val.z = (unsigned int)hi; val.w = (unsigned int)(hi >> 32);
                sB[kt * 64 + l] = val;
            }
        }
        __syncthreads();
        // 12 MFMAs: D[row][slot] = sum_k W[row][k] * act[slot][k] + bias
        {
            f32x4 acc = bias;
#pragma unroll
            for (int kt = 0; kt < 12; ++kt) {
                const f16x8 bfr = ((const f16x8*)sB)[kt * 64 + lane];
                acc = __builtin_amdgcn_mfma_f32_16x16x32_f16(afr[kt], bfr, acc, 0, 0, 0);
            }
            const int n = lane & 15, rbase = 16 * wv + (lane >> 4) * 4;
#pragma unroll
            for (int r = 0; r < 4; ++r) sG[rbase + r][n] = acc[r];
        }
        __syncthreads();
        // cell update + packed h publish (torch gate order i,f,g,o)
        {
            const int k = tid >> 5, u = tid & 31;
            const int v = sNode[k];
            const bool act = (sStep[k] >= 0);
            float hn = 0.0f;
            if (act) {
                const float gi = sG[u][k],      gf = sG[32 + u][k];
                const float gg = sG[64 + u][k], go = sG[96 + u][k];
                const float cn = sigm(gf) * sC[k][u] + sigm(gi) * tanhf(gg);
                sC[k][u] = cn;
                hn = sigm(go) * tanhf(cn);
            }
            const float hn1 = __shfl_down(hn, 1);
            if (act) {
                if ((u & 1) == 0) {
                    unsigned int* dst = (unsigned int*)g_hpk4[tick & 1][v];
                    __hip_atomic_store(&dst[(j << 4) + (u >> 1)], pkh(hn, hn1),
                                       __ATOMIC_RELAXED, __HIP_MEMORY_SCOPE_AGENT);
                }
                if (tick == sLen[k] - 1) g_hid[v][(j << 5) + u] = hn;  // final f32 for decoder
            }
        }
        __syncthreads();   // drain all waves' h stores before flag
        if (tid == 0)
            __hip_atomic_store(&g_tflag[c][j], tick + 1, __ATOMIC_RELAXED,
                               __HIP_MEMORY_SCOPE_AGENT);
    }
}

// ---------------- decoder: logits + log_softmax ----------------
__global__ __launch_bounds__(256) void k_decode(const float* __restrict__ dec_W,
                                                const float* __restrict__ dec_b,
                                                float* __restrict__ out) {
    const int gtid = blockIdx.x * 256 + threadIdx.x;
    const int row = gtid >> 4, lane = gtid & 15;   // row = p*NN + n
    const int p = row >> 9, n = row & (NN - 1);
    const float* dw = dec_W + (p * OUTC + lane) * HID;
    float acc = dec_b[p * OUTC + lane];
#pragma unroll 8
    for (int j = 0; j < HID; j += 4) {
        const float4 hv = *(const float4*)&g_hid[n][j];
        const float4 wv = *(const float4*)(dw + j);
        acc += hv.x * wv.x + hv.y * wv.y + hv.z * wv.z + hv.w * wv.w;
    }
    float mx = acc;
    mx = fmaxf(mx, __shfl_xor(mx, 1));
    mx = fmaxf(mx, __shfl_xor(mx, 2));
    mx = fmaxf(mx, __shfl_xor(mx, 4));
    mx = fmaxf(mx, __shfl_xor(mx, 8));
    float s = expf(acc - mx);
    s += __shfl_xor(s, 1);
    s += __shfl_xor(s, 2);
    s += __shfl_xor(s, 4);
    s += __shfl_xor(s, 8);
    out[row * OUTC + lane] = acc - mx - logf(s);
}

extern "C" void kernel_launch(void* const* d_in, const int* in_sizes, int n_in,
                              void* d_out, int out_size, void* d_ws, size_t ws_size,
                              hipStream_t stream) {
    (void)in_sizes; (void)n_in; (void)out_size; (void)d_ws; (void)ws_size;
    const float* xa   = (const float*)d_in[0];
    const float* fm   = (const float*)d_in[1];
    const int*   ei   = (const int*)d_in[2];
    const int*   st   = (const int*)d_in[3];
    const float* encW = (const float*)d_in[4];
    const float* encb = (const float*)d_in[5];
    const float* Wih  = (const float*)d_in[6];
    const float* Whh  = (const float*)d_in[7];
    const float* bih  = (const float*)d_in[8];
    const float* bhh  = (const float*)d_in[9];
    const float* nmW  = (const float*)d_in[10];
    const float* nmb  = (const float*)d_in[11];
    const float* decW = (const float*)d_in[12];
    const float* decb = (const float*)d_in[13];
    float* out = (float*)d_out;

    hipLaunchKernelGGL(k_setup,  dim3(1728),            dim3(256),  0, stream,
                       xa, encW, encb, Wih, Whh, bih, bhh, nmW, ei);
    hipLaunchKernelGGL(k_sched,  dim3(1),               dim3(1024), 0, stream, st);
    hipLaunchKernelGGL(k_lists2, dim3(NN + NWGA + 256), dim3(256),  0, stream, fm);
    hipLaunchKernelGGL(k_phaseA, dim3(NWGA),            dim3(512),  0, stream, nmb);
    hipLaunchKernelGGL(k_phaseB, dim3(NCLUS * WPC),     dim3(512),  0, stream);
    hipLaunchKernelGGL(k_decode, dim3(128),             dim3(256),  0, stream, decW, decb, out);
}